// Round 8
// baseline (282.136 us; speedup 1.0000x reference)
//
#include <hip/hip_runtime.h>
#include <hip/hip_bf16.h>
#include <stdint.h>

typedef __bf16 bf16x8  __attribute__((ext_vector_type(8)));
typedef __bf16 bf16x4  __attribute__((ext_vector_type(4)));
typedef __bf16 bf16x16 __attribute__((ext_vector_type(16)));
typedef float  f32x4   __attribute__((ext_vector_type(4)));
typedef float  f32x16  __attribute__((ext_vector_type(16)));
typedef uint32_t u32;

#define MFMA16(a, b, c) __builtin_amdgcn_mfma_f32_16x16x32_bf16((a), (b), (c), 0, 0, 0)
#define MFMA32(a, b, c) __builtin_amdgcn_mfma_f32_32x32x16_bf16((a), (b), (c), 0, 0, 0)

constexpr int CH = 160, CW = 160, CC = 192, CHEADS = 6, CD = 32;
constexpr int CNQ = 256, CNKV = 576, CPH = 168;
constexpr int CPL = CPH * CPH;           // 28224 per (b,head,d) V-plane
constexpr float LOG2E = 1.44269504088896340736f;
constexpr float QSCALE_L2E = 0.17677669529663687f * 1.44269504088896340736f;

// ---------------------------------------------------------------------------
// bf16 bias table (1.77 MB, L2-resident):
// bth[((head*8 + qtg)*18 + ktg)*64 + lane][16]
// ---------------------------------------------------------------------------
__global__ __launch_bounds__(256)
void biash_k(const int* __restrict__ rpi, const float* __restrict__ tab,
             __bf16* __restrict__ bth)
{
    int idx = blockIdx.x * 256 + threadIdx.x;  // 55296
    int lane = idx & 63;
    int rest = idx >> 6;
    int ktg = rest % 18; rest /= 18;
    int qtg = rest & 7;
    int head = rest >> 3;
    int l31 = lane & 31, hi = lane >> 5;
    int q = qtg * 32 + l31;

    bf16x16 o16;
#pragma unroll
    for (int g = 0; g < 4; ++g) {
        int4 ri = *(const int4*)(rpi + q * CNKV + ktg * 32 + 4 * hi + g * 8);
        o16[g * 4 + 0] = (__bf16)(tab[ri.x * CHEADS + head] * LOG2E);
        o16[g * 4 + 1] = (__bf16)(tab[ri.y * CHEADS + head] * LOG2E);
        o16[g * 4 + 2] = (__bf16)(tab[ri.z * CHEADS + head] * LOG2E);
        o16[g * 4 + 3] = (__bf16)(tab[ri.w * CHEADS + head] * LOG2E);
    }
    *(bf16x16*)(bth + (long)idx * 16) = o16;
}

// ---------------------------------------------------------------------------
// Validity bitmask MT[cls 9][ktg 18][lane 64]
// ---------------------------------------------------------------------------
__global__ __launch_bounds__(256)
void mask_k(u32* __restrict__ mt)
{
    int idx = blockIdx.x * 256 + threadIdx.x;  // 10368
    if (idx >= 9 * 18 * 64) return;
    int lane = idx & 63;
    int rest = idx >> 6;
    int ktg = rest % 18;
    int cls = rest / 18;
    int cy = cls / 3, cx = cls % 3;
    int hi = lane >> 5;
    u32 m = 0;
#pragma unroll
    for (int r = 0; r < 16; ++r) {
        int kv = ktg * 32 + 4 * hi + (r & 3) + 8 * (r >> 2);
        int oy = kv / 24, ox = kv - oy * 24;
        bool vy = (cy == 0) ? (oy >= 4) : ((cy == 2) ? (oy < 20) : true);
        bool vx = (cx == 0) ? (ox >= 4) : ((cx == 2) ? (ox < 20) : true);
        if (vy && vx) m |= (1u << r);
    }
    mt[idx] = m;
}

// ---------------------------------------------------------------------------
// Weight transpose+fuse: Wt[768][192] = [q_w*s | g_w | kv_w]^T bf16,
// Wp[192][192] = p_w^T bf16, b768 = [q_b*s | g_b | kv_b] f32, pb = p_b f32.
// ---------------------------------------------------------------------------
__global__ __launch_bounds__(256)
void wtrans_k(const float* __restrict__ q_w, const float* __restrict__ g_w,
              const float* __restrict__ kv_w, const float* __restrict__ p_w,
              const float* __restrict__ q_b, const float* __restrict__ g_b,
              const float* __restrict__ kv_b, const float* __restrict__ p_b,
              __bf16* __restrict__ Wt, __bf16* __restrict__ Wp,
              float* __restrict__ b768, float* __restrict__ pb)
{
    int idx = blockIdx.x * 256 + threadIdx.x;
    if (idx < 147456) {
        int n = idx / 192, k = idx - n * 192;
        float v;
        if (n < 192)      v = q_w[k * 192 + n] * QSCALE_L2E;
        else if (n < 384) v = g_w[k * 192 + (n - 192)];
        else              v = kv_w[k * 384 + (n - 384)];
        Wt[idx] = (__bf16)v;
    } else if (idx < 184320) {
        int j = idx - 147456;
        int n = j / 192, k = j - n * 192;
        Wp[j] = (__bf16)p_w[k * 192 + n];
    } else if (idx < 185280) {
        int j = idx - 184320;
        if (j < 192)      b768[j] = q_b[j] * QSCALE_L2E;
        else if (j < 384) b768[j] = g_b[j - 192];
        else if (j < 768) b768[j] = kv_b[j - 384];
        else              pb[j - 768] = p_b[j - 768];
    }
}

// ---------------------------------------------------------------------------
// Pad fill, K rows: Kb[b][168][168][192] border rows <- kv_b[0..191]
// ---------------------------------------------------------------------------
__global__ __launch_bounds__(256)
void padk_k(const float* __restrict__ kv_b, __bf16* __restrict__ Kb)
{
    int tid = blockIdx.x * 256 + threadIdx.x;   // 5248 rows * 24 segs = 125952
    if (tid >= 125952) return;
    int row = tid / 24, seg = tid - row * 24;
    int bb = row / 2624, rr = row - bb * 2624;
    int py, px;
    if (rr < 672)       { py = rr / 168;               px = rr % 168; }
    else if (rr < 1344) { int r2 = rr - 672; py = 164 + r2 / 168; px = r2 % 168; }
    else                { int rm = rr - 1344; py = 4 + rm / 8; int q = rm & 7;
                          px = (q < 4) ? q : 160 + q; }
    bf16x8 v;
#pragma unroll
    for (int j = 0; j < 8; ++j) v[j] = (__bf16)kv_b[seg * 8 + j];
    *(bf16x8*)(Kb + ((long)((bb * CPH + py) * CPH + px)) * 192 + seg * 8) = v;
}

// ---------------------------------------------------------------------------
// Pad fill, V planes: VTg[(b*6+head)*32+d][168][168] border <- kv_b[192+head*32+d]
// ---------------------------------------------------------------------------
__global__ __launch_bounds__(256)
void padv_k(const float* __restrict__ kv_b, __bf16* __restrict__ VTg)
{
    int tid = blockIdx.x * 256 + threadIdx.x;   // 384 planes * 328 tasks = 125952
    if (tid >= 125952) return;
    int plane = tid / 328, c8 = (tid - plane * 328) * 8;
    int d = plane & 31, head = (plane >> 5) % 6;
    __bf16 val = (__bf16)kv_b[192 + head * 32 + d];
    __bf16* base = VTg + (long)plane * CPL;
    if (c8 < 1344) {
        int py, px;
        if (c8 < 672) { py = c8 / 168; px = c8 % 168; }
        else          { int r2 = c8 - 672; py = 164 + r2 / 168; px = r2 % 168; }
        bf16x8 v;
#pragma unroll
        for (int j = 0; j < 8; ++j) v[j] = val;
        *(bf16x8*)(base + (long)py * CPH + px) = v;
    } else {
        int cm = c8 - 1344;
        int py = 4 + cm / 8;
        bf16x4 v;
#pragma unroll
        for (int j = 0; j < 4; ++j) v[j] = val;
        *(bf16x4*)(base + (long)py * CPH) = v;
        *(bf16x4*)(base + (long)py * CPH + 164) = v;
    }
}

// ---------------------------------------------------------------------------
// Fused QGKV GEMM: M=51200 image rows, N=768 (Q|G|K|V), K=192.
// BM=BN=BK=64, reg-staged XOR-swizzled LDS, double-buffered.
// Epilogue: Q,G -> window bf16; K -> padded image [*][192]; V -> VTg d-major.
// ---------------------------------------------------------------------------
__global__ __launch_bounds__(256)
void gemm_f_k(const float* __restrict__ x, const __bf16* __restrict__ Wt,
              const float* __restrict__ b768,
              __bf16* __restrict__ Qb, __bf16* __restrict__ Gb,
              __bf16* __restrict__ Kb, __bf16* __restrict__ VTg)
{
    __shared__ __bf16 As[2][4096];
    __shared__ __bf16 Bs[2][4096];

    const int bid = blockIdx.x;                 // 9600 = 8 * 1200
    const int v = (bid & 7) * 1200 + (bid >> 3);
    const int bm = v / 12, bn = v - bm * 12;

    const int t = threadIdx.x, lane = t & 63, wv = t >> 6;
    const int l15 = lane & 15, l4 = lane >> 4;
    const int row = t >> 2, gp = t & 3;
    const int swz = row & 7;
    const int d0 = row * 64 + ((2 * gp) ^ swz) * 8;
    const int d1 = row * 64 + ((2 * gp + 1) ^ swz) * 8;

    const float*  asrc = x  + (long)(bm * 64 + row) * 192 + gp * 16;
    const __bf16* bsrc = Wt + (long)(bn * 64 + row) * 192 + gp * 16;

    float4 fa0, fa1, fa2, fa3;
    bf16x8 wb0, wb1;
    auto ld = [&](int kt) {
        const float* a = asrc + kt * 64;
        fa0 = ((const float4*)a)[0]; fa1 = ((const float4*)a)[1];
        fa2 = ((const float4*)a)[2]; fa3 = ((const float4*)a)[3];
        wb0 = *(const bf16x8*)(bsrc + kt * 64);
        wb1 = *(const bf16x8*)(bsrc + kt * 64 + 8);
    };
    auto st = [&](int buf) {
        bf16x8 g0, g1;
        g0[0] = (__bf16)fa0.x; g0[1] = (__bf16)fa0.y; g0[2] = (__bf16)fa0.z; g0[3] = (__bf16)fa0.w;
        g0[4] = (__bf16)fa1.x; g0[5] = (__bf16)fa1.y; g0[6] = (__bf16)fa1.z; g0[7] = (__bf16)fa1.w;
        g1[0] = (__bf16)fa2.x; g1[1] = (__bf16)fa2.y; g1[2] = (__bf16)fa2.z; g1[3] = (__bf16)fa2.w;
        g1[4] = (__bf16)fa3.x; g1[5] = (__bf16)fa3.y; g1[6] = (__bf16)fa3.z; g1[7] = (__bf16)fa3.w;
        *(bf16x8*)&As[buf][d0] = g0;
        *(bf16x8*)&As[buf][d1] = g1;
        *(bf16x8*)&Bs[buf][d0] = wb0;
        *(bf16x8*)&Bs[buf][d1] = wb1;
    };

    const int qm = (wv >> 1) * 32, qn = (wv & 1) * 32;
    f32x4 acc[2][2];
#pragma unroll
    for (int i = 0; i < 2; ++i)
#pragma unroll
        for (int j = 0; j < 2; ++j) acc[i][j] = f32x4{0.f, 0.f, 0.f, 0.f};

    ld(0);
    for (int kt = 0; kt < 3; ++kt) {
        const int buf = kt & 1;
        st(buf);
        if (kt < 2) ld(kt + 1);
        __syncthreads();
#pragma unroll
        for (int s = 0; s < 2; ++s) {
            bf16x8 af[2], bfr[2];
#pragma unroll
            for (int mi = 0; mi < 2; ++mi)
                af[mi] = *(const bf16x8*)&As[buf][(qm + mi * 16 + l15) * 64 +
                                                 (((s * 4 + l4) ^ (l15 & 7)) * 8)];
#pragma unroll
            for (int ni = 0; ni < 2; ++ni)
                bfr[ni] = *(const bf16x8*)&Bs[buf][(qn + ni * 16 + l15) * 64 +
                                                   (((s * 4 + l4) ^ (l15 & 7)) * 8)];
#pragma unroll
            for (int mi = 0; mi < 2; ++mi)
#pragma unroll
                for (int ni = 0; ni < 2; ++ni)
                    acc[mi][ni] = MFMA16(af[mi], bfr[ni], acc[mi][ni]);
        }
        __syncthreads();
    }

#pragma unroll
    for (int mi = 0; mi < 2; ++mi) {
#pragma unroll
        for (int r = 0; r < 4; ++r) {
            int rowg = bm * 64 + qm + mi * 16 + l4 * 4 + r;
            int bb = rowg / 25600, rr = rowg - bb * 25600;
            int y = rr / 160, xx = rr - y * 160;
            int win = bb * 100 + (y >> 4) * 10 + (xx >> 4);
            long widx = ((long)win * 256 + (y & 15) * 16 + (xx & 15)) * 192;
            long kidx = ((long)((bb * CPH + y + 4) * CPH + (xx + 4))) * 192;
            long vpos = (long)(y + 4) * CPH + (xx + 4);
#pragma unroll
            for (int ni = 0; ni < 2; ++ni) {
                int cg = bn * 64 + qn + ni * 16 + l15;
                float val = acc[mi][ni][r] + b768[cg];
                if (cg < 192)       Qb[widx + cg] = (__bf16)val;
                else if (cg < 384)  Gb[widx + cg - 192] = (__bf16)val;
                else if (cg < 576)  Kb[kidx + cg - 384] = (__bf16)val;
                else {
                    int vv = cg - 576;
                    int plane = (bb * 6 + (vv >> 5)) * 32 + (vv & 31);
                    VTg[(long)plane * CPL + vpos] = (__bf16)val;
                }
            }
        }
    }
}

// ---------------------------------------------------------------------------
// Projection GEMM: M=51200 window rows (Yb), N=192, K=192; out f32 image.
// ---------------------------------------------------------------------------
__global__ __launch_bounds__(256)
void gemm_p_k(const __bf16* __restrict__ Yb, const __bf16* __restrict__ Wp,
              const float* __restrict__ pb, float* __restrict__ of)
{
    __shared__ __bf16 As[2][4096];
    __shared__ __bf16 Bs[2][4096];

    const int bid = blockIdx.x;                 // 2400 = 8 * 300
    const int v = (bid & 7) * 300 + (bid >> 3);
    const int bm = v / 3, bn = v - bm * 3;

    const int t = threadIdx.x, lane = t & 63, wv = t >> 6;
    const int l15 = lane & 15, l4 = lane >> 4;
    const int row = t >> 2, gp = t & 3;
    const int swz = row & 7;
    const int d0 = row * 64 + ((2 * gp) ^ swz) * 8;
    const int d1 = row * 64 + ((2 * gp + 1) ^ swz) * 8;

    const __bf16* asrc = Yb + (long)(bm * 64 + row) * 192 + gp * 16;
    const __bf16* bsrc = Wp + (long)(bn * 64 + row) * 192 + gp * 16;

    bf16x8 a0, a1, wb0, wb1;
    auto ld = [&](int kt) {
        a0  = *(const bf16x8*)(asrc + kt * 64);
        a1  = *(const bf16x8*)(asrc + kt * 64 + 8);
        wb0 = *(const bf16x8*)(bsrc + kt * 64);
        wb1 = *(const bf16x8*)(bsrc + kt * 64 + 8);
    };
    auto st = [&](int buf) {
        *(bf16x8*)&As[buf][d0] = a0;
        *(bf16x8*)&As[buf][d1] = a1;
        *(bf16x8*)&Bs[buf][d0] = wb0;
        *(bf16x8*)&Bs[buf][d1] = wb1;
    };

    const int qm = (wv >> 1) * 32, qn = (wv & 1) * 32;
    f32x4 acc[2][2];
#pragma unroll
    for (int i = 0; i < 2; ++i)
#pragma unroll
        for (int j = 0; j < 2; ++j) acc[i][j] = f32x4{0.f, 0.f, 0.f, 0.f};

    ld(0);
    for (int kt = 0; kt < 3; ++kt) {
        const int buf = kt & 1;
        st(buf);
        if (kt < 2) ld(kt + 1);
        __syncthreads();
#pragma unroll
        for (int s = 0; s < 2; ++s) {
            bf16x8 af[2], bfr[2];
#pragma unroll
            for (int mi = 0; mi < 2; ++mi)
                af[mi] = *(const bf16x8*)&As[buf][(qm + mi * 16 + l15) * 64 +
                                                 (((s * 4 + l4) ^ (l15 & 7)) * 8)];
#pragma unroll
            for (int ni = 0; ni < 2; ++ni)
                bfr[ni] = *(const bf16x8*)&Bs[buf][(qn + ni * 16 + l15) * 64 +
                                                   (((s * 4 + l4) ^ (l15 & 7)) * 8)];
#pragma unroll
            for (int mi = 0; mi < 2; ++mi)
#pragma unroll
                for (int ni = 0; ni < 2; ++ni)
                    acc[mi][ni] = MFMA16(af[mi], bfr[ni], acc[mi][ni]);
        }
        __syncthreads();
    }

#pragma unroll
    for (int mi = 0; mi < 2; ++mi) {
#pragma unroll
        for (int r = 0; r < 4; ++r) {
            int rowg = bm * 64 + qm + mi * 16 + l4 * 4 + r;   // window row
            int win = rowg >> 8, q = rowg & 255;
            int bb = win / 100, wr = win % 100;
            int y = (wr / 10) * 16 + (q >> 4), xx = (wr % 10) * 16 + (q & 15);
            long oidx = ((long)((bb * CH + y) * CW + xx)) * 192;
#pragma unroll
            for (int ni = 0; ni < 2; ++ni) {
                int cg = bn * 64 + qn + ni * 16 + l15;
                of[oidx + cg] = acc[mi][ni][r] + pb[cg];
            }
        }
    }
}

// ---------------------------------------------------------------------------
// Attention v8: K-only LDS (41.5 KB -> 3 blocks/CU, 6 waves/SIMD); V read
// directly from the d-major transposed global buffer VTg (L2-resident, 8-B
// contiguous per 4-kv run, division-free incremental pointers). Zero barriers
// in the main loop; K-frag + bias prefetched one tile ahead. Same math.
// ---------------------------------------------------------------------------
__global__ __launch_bounds__(512, 6)
void attn8_k(const __bf16* __restrict__ Q, const __bf16* __restrict__ Kb,
             const __bf16* __restrict__ VTg, const __bf16* __restrict__ G,
             const __bf16* __restrict__ BTh, const u32* __restrict__ MT,
             __bf16* __restrict__ Y)
{
    __shared__ __bf16 Ks[576][36];   // 41,472 B

    const int bid = blockIdx.x;      // 1200 = 8 * 150
    const int xs = bid & 7, ii = bid >> 3;
    const int win = xs * 25 + ii / 6;
    const int head = ii % 6;

    const int bb = win / 100, wr = win % 100, wy = wr / 10, wx = wr % 10;
    const int cy = (wy == 0) ? 0 : ((wy == 9) ? 2 : 1);
    const int cx = (wx == 0) ? 0 : ((wx == 9) ? 2 : 1);
    const int cls = cy * 3 + cx;
    const int t = threadIdx.x, lane = t & 63, wv = t >> 6;
    const int l31 = lane & 31, hi = lane >> 5;

    // ---- stage K (this head's 32-d slice of all 576 kv rows) ----
    {
        const int pos0 = t >> 2, seg = t & 3;    // 128 rows/pass
        int oy = pos0 / 24, ox = pos0 % 24;
        const __bf16* kb = Kb + ((long)((bb * CPH + wy * 16) * CPH + wx * 16)) * 192
                           + head * 32 + seg * 8;
        int pos = pos0;
#pragma unroll
        for (int r = 0; r < 5; ++r) {
            if (pos < 576) {
                bf16x8 k8 = *(const bf16x8*)(kb + (long)(oy * CPH + ox) * 192);
                *(bf16x8*)&Ks[pos][seg * 8] = k8;
            }
            pos += 128;
            oy += 5; ox += 8;
            if (ox >= 24) { ox -= 24; oy += 1; }
        }
    }

    // Q fragments (this wave's 32 q-rows)
    bf16x8 qf0, qf1;
    {
        const __bf16* qb = Q + ((long)win * CNQ + wv * 32 + l31) * CC + head * CD;
        qf0 = *(const bf16x8*)(qb + hi * 8);
        qf1 = *(const bf16x8*)(qb + 16 + hi * 8);
    }
    const __bf16* btb = BTh + (long)((head * 8 + wv) * 18) * 1024 + (long)lane * 16;
    bf16x16 bA = *(const bf16x16*)btb;

    // V pointers: 4 slot-groups, kv(tile 0) = g*8 + 4*hi
    const __bf16* vbase = VTg + ((long)((bb * 6 + head) * 32 + l31)) * CPL
                          + (long)(wy * 16) * CPH + wx * 16;
    const __bf16 *vp0, *vp1, *vp2, *vp3;
    int ox0, ox1, ox2, ox3;
    {
        int k0 = 4 * hi,      k1 = 8 + 4 * hi;
        int k2 = 16 + 4 * hi, k3 = 24 + 4 * hi;
        ox0 = k0; ox1 = k1; ox2 = k2;                 // all < 24
        int oy3 = k3 / 24;  ox3 = k3 - oy3 * 24;
        vp0 = vbase + ox0;
        vp1 = vbase + ox1;
        vp2 = vbase + ox2;
        vp3 = vbase + oy3 * CPH + ox3;
    }

    __syncthreads();   // the ONLY barrier

    f32x16 o = {};
    float srun = 0.f;

    const char* kbase = (const char*)&Ks[0][0] + l31 * 72 + hi * 16;
    bf16x8 kc0 = *(const bf16x8*)(kbase);
    bf16x8 kc1 = *(const bf16x8*)(kbase + 32);

    for (int tt = 0; tt < 18; ++tt) {
        // prefetch next tile's K frags (LDS) + bias (L2)
        bf16x8 kn0, kn1;
        bf16x16 bB;
        if (tt < 17) {
            const char* kn = kbase + (tt + 1) * 2304;
            kn0 = *(const bf16x8*)(kn);
            kn1 = *(const bf16x8*)(kn + 32);
            bB  = *(const bf16x16*)(btb + (long)(tt + 1) * 1024);
        }

        // V fragments (global, L2-resident, 8B each)
        bf16x4 v0 = *(const bf16x4*)vp0;
        bf16x4 v1 = *(const bf16x4*)vp1;
        bf16x4 v2 = *(const bf16x4*)vp2;
        bf16x4 v3 = *(const bf16x4*)vp3;
        // advance kv += 32 (division-free)
        {
            bool w0 = ox0 >= 16; vp0 += w0 ? (2 * CPH - 16) : (CPH + 8); ox0 = w0 ? ox0 - 16 : ox0 + 8;
            bool w1 = ox1 >= 16; vp1 += w1 ? (2 * CPH - 16) : (CPH + 8); ox1 = w1 ? ox1 - 16 : ox1 + 8;
            bool w2 = ox2 >= 16; vp2 += w2 ? (2 * CPH - 16) : (CPH + 8); ox2 = w2 ? ox2 - 16 : ox2 + 8;
            bool w3 = ox3 >= 16; vp3 += w3 ? (2 * CPH - 16) : (CPH + 8); ox3 = w3 ? ox3 - 16 : ox3 + 8;
        }
        bf16x8 vf0, vf1;
#pragma unroll
        for (int j = 0; j < 4; ++j) {
            vf0[j] = v0[j]; vf0[4 + j] = v1[j];
            vf1[j] = v2[j]; vf1[4 + j] = v3[j];
        }

        // scores = bias + K^T Q
        f32x16 stv;
#pragma unroll
        for (int r = 0; r < 16; ++r) stv[r] = (float)bA[r];
        __builtin_amdgcn_s_setprio(1);
        stv = MFMA32(kc0, qf0, stv);
        stv = MFMA32(kc1, qf1, stv);
        __builtin_amdgcn_s_setprio(0);

        const bool needm = (cx != 1) || (cy == 0 && tt < 3) || (cy == 2 && tt >= 15);
        u32 m = 0xFFFFFFFFu;
        if (needm) m = MT[(cls * 18 + tt) * 64 + lane];

        float p[16];
#pragma unroll
        for (int r = 0; r < 16; ++r) p[r] = exp2f(stv[r]);
        if (needm) {
#pragma unroll
            for (int r = 0; r < 16; ++r)
                p[r] = (m & (1u << r)) ? p[r] : 0.0f;
        }
        float s = 0.f;
#pragma unroll
        for (int r = 0; r < 16; ++r) s += p[r];
        srun += s;

        bf16x8 pa0, pa1;
#pragma unroll
        for (int j = 0; j < 8; ++j) {
            pa0[j] = (__bf16)p[j];
            pa1[j] = (__bf16)p[8 + j];
        }

        __builtin_amdgcn_s_setprio(1);
        o = MFMA32(vf0, pa0, o);
        o = MFMA32(vf1, pa1, o);
        __builtin_amdgcn_s_setprio(0);

        kc0 = kn0; kc1 = kn1; bA = bB;
    }

    // ---- epilogue: cross-half sum, normalize, gate, store ----
    srun += __shfl_xor(srun, 32);
    float rs = 1.0f / srun;
    long base = ((long)win * CNQ + wv * 32 + l31) * CC + head * CD;
    const __bf16* gp2 = G + base;
    __bf16* yp = Y + base;
#pragma unroll
    for (int g = 0; g < 4; ++g) {
        bf16x4 gv = *(const bf16x4*)(gp2 + g * 8 + 4 * hi);
        bf16x4 ov;
#pragma unroll
        for (int j = 0; j < 4; ++j)
            ov[j] = (__bf16)(o[g * 4 + j] * rs * (float)gv[j]);
        *(bf16x4*)(yp + g * 8 + 4 * hi) = ov;
    }
}

// ---------------------------------------------------------------------------
extern "C" void kernel_launch(void* const* d_in, const int* in_sizes, int n_in,
                              void* d_out, int out_size, void* d_ws, size_t ws_size,
                              hipStream_t stream)
{
    (void)in_sizes; (void)n_in; (void)out_size; (void)ws_size;
    const float* x    = (const float*)d_in[0];
    const int*   rpi  = (const int*)  d_in[1];
    // d_in[2] = attn_mask (recomputed analytically)
    const float* q_w  = (const float*)d_in[3];
    const float* q_b  = (const float*)d_in[4];
    const float* kv_w = (const float*)d_in[5];
    const float* kv_b = (const float*)d_in[6];
    const float* btab = (const float*)d_in[7];
    const float* g_w  = (const float*)d_in[8];
    const float* g_b  = (const float*)d_in[9];
    const float* p_w  = (const float*)d_in[10];
    const float* p_b  = (const float*)d_in[11];
    float* out = (float*)d_out;

    char* ws = (char*)d_ws;
    __bf16* Qb  = (__bf16*)(ws);                  // 19,660,800
    __bf16* Kb  = (__bf16*)(ws + 19660800);       // 21,676,032
    __bf16* VTg = (__bf16*)(ws + 41336832);       // 21,676,032
    __bf16* Gb  = (__bf16*)(ws + 63012864);       // 19,660,800
    __bf16* Yb  = (__bf16*)(ws + 82673664);       // 19,660,800
    __bf16* BTh = (__bf16*)(ws + 102334464);      // 1,769,472
    u32*    MT  = (u32*)   (ws + 104103936);      // 41,472
    __bf16* Wt  = (__bf16*)(ws + 104145408);      // 294,912
    __bf16* Wp  = (__bf16*)(ws + 104440320);      // 73,728
    float*  b768= (float*) (ws + 104514048);      // 3,072
    float*  pb  = (float*) (ws + 104517120);      // 768

    biash_k<<<216, 256, 0, stream>>>(rpi, btab, BTh);
    mask_k<<<41, 256, 0, stream>>>(MT);
    wtrans_k<<<724, 256, 0, stream>>>(q_w, g_w, kv_w, p_w, q_b, g_b, kv_b, p_b,
                                      Wt, Wp, b768, pb);
    padk_k<<<492, 256, 0, stream>>>(kv_b, Kb);
    padv_k<<<492, 256, 0, stream>>>(kv_b, VTg);
    gemm_f_k<<<9600, 256, 0, stream>>>(x, Wt, b768, Qb, Gb, Kb, VTg);
    attn8_k<<<1200, 512, 0, stream>>>(Qb, Kb, VTg, Gb, BTh, MT, Yb);
    gemm_p_k<<<2400, 256, 0, stream>>>(Yb, Wp, pb, out);
}

// Round 9
// 147.556 us; speedup vs baseline: 1.9121x; 1.9121x over previous
//
#include <hip/hip_runtime.h>
#include <hip/hip_bf16.h>
#include <stdint.h>

typedef __bf16 bf16x8  __attribute__((ext_vector_type(8)));
typedef __bf16 bf16x4  __attribute__((ext_vector_type(4)));
typedef __bf16 bf16x16 __attribute__((ext_vector_type(16)));
typedef float  f32x4   __attribute__((ext_vector_type(4)));
typedef float  f32x16  __attribute__((ext_vector_type(16)));
typedef uint32_t u32;

#define MFMA16(a, b, c) __builtin_amdgcn_mfma_f32_16x16x32_bf16((a), (b), (c), 0, 0, 0)
#define MFMA32(a, b, c) __builtin_amdgcn_mfma_f32_32x32x16_bf16((a), (b), (c), 0, 0, 0)

constexpr int CH = 160, CW = 160, CC = 192, CHEADS = 6, CD = 32;
constexpr int CNQ = 256, CNKV = 576, CPH = 168;
constexpr float LOG2E = 1.44269504088896340736f;
constexpr float QSCALE_L2E = 0.17677669529663687f * 1.44269504088896340736f;

// ---------------------------------------------------------------------------
// Merged prep kernel. Block ranges:
//   [0,216)    : f32 bias table BTf[((head*8+qtg)*18+ktg)*64+lane][16]
//   [216,257)  : validity bitmask MT[cls 9][ktg 18][lane 64]
//   [257,981)  : weight transpose/fuse Wt, Wp, b768, pb
//   [981,1965) : KVb border fill with kv_b
// ---------------------------------------------------------------------------
__global__ __launch_bounds__(256)
void prep_k(const int* __restrict__ rpi, const float* __restrict__ tab,
            const float* __restrict__ q_w, const float* __restrict__ g_w,
            const float* __restrict__ kv_w, const float* __restrict__ p_w,
            const float* __restrict__ q_b, const float* __restrict__ g_b,
            const float* __restrict__ kv_b, const float* __restrict__ p_b,
            float* __restrict__ BTf, u32* __restrict__ mt,
            __bf16* __restrict__ Wt, __bf16* __restrict__ Wp,
            float* __restrict__ b768, float* __restrict__ pb,
            __bf16* __restrict__ KVb)
{
    const int bidg = blockIdx.x;
    if (bidg < 216) {
        int idx = bidg * 256 + threadIdx.x;  // 55296
        int lane = idx & 63;
        int rest = idx >> 6;
        int ktg = rest % 18; rest /= 18;
        int qtg = rest & 7;
        int head = rest >> 3;
        int l31 = lane & 31, hi = lane >> 5;
        int q = qtg * 32 + l31;
        float bv[16];
#pragma unroll
        for (int g = 0; g < 4; ++g) {
            int4 ri = *(const int4*)(rpi + q * CNKV + ktg * 32 + 4 * hi + g * 8);
            bv[g * 4 + 0] = tab[ri.x * CHEADS + head] * LOG2E;
            bv[g * 4 + 1] = tab[ri.y * CHEADS + head] * LOG2E;
            bv[g * 4 + 2] = tab[ri.z * CHEADS + head] * LOG2E;
            bv[g * 4 + 3] = tab[ri.w * CHEADS + head] * LOG2E;
        }
        float* dst = BTf + (long)idx * 16;
#pragma unroll
        for (int g = 0; g < 4; ++g)
            *(float4*)(dst + g * 4) = *(float4*)&bv[g * 4];
    } else if (bidg < 257) {
        int idx = (bidg - 216) * 256 + threadIdx.x;
        if (idx >= 9 * 18 * 64) return;
        int lane = idx & 63;
        int rest = idx >> 6;
        int ktg = rest % 18;
        int cls = rest / 18;
        int cy = cls / 3, cx = cls % 3;
        int hi = lane >> 5;
        u32 m = 0;
#pragma unroll
        for (int r = 0; r < 16; ++r) {
            int kv = ktg * 32 + 4 * hi + (r & 3) + 8 * (r >> 2);
            int oy = kv / 24, ox = kv - oy * 24;
            bool vy = (cy == 0) ? (oy >= 4) : ((cy == 2) ? (oy < 20) : true);
            bool vx = (cx == 0) ? (ox >= 4) : ((cx == 2) ? (ox < 20) : true);
            if (vy && vx) m |= (1u << r);
        }
        mt[idx] = m;
    } else if (bidg < 981) {
        int idx = (bidg - 257) * 256 + threadIdx.x;
        if (idx < 147456) {
            int n = idx / 192, k = idx - n * 192;
            float v;
            if (n < 192)      v = q_w[k * 192 + n] * QSCALE_L2E;
            else if (n < 384) v = g_w[k * 192 + (n - 192)];
            else              v = kv_w[k * 384 + (n - 384)];
            Wt[idx] = (__bf16)v;
        } else if (idx < 184320) {
            int j = idx - 147456;
            int n = j / 192, k = j - n * 192;
            Wp[j] = (__bf16)p_w[k * 192 + n];
        } else if (idx < 185280) {
            int j = idx - 184320;
            if (j < 192)      b768[j] = q_b[j] * QSCALE_L2E;
            else if (j < 384) b768[j] = g_b[j - 192];
            else if (j < 768) b768[j] = kv_b[j - 384];
            else              pb[j - 768] = p_b[j - 768];
        }
    } else {
        int tid = (bidg - 981) * 256 + threadIdx.x;  // 5248 rows * 48 segs
        if (tid >= 251904) return;
        int row = tid / 48, seg = tid - row * 48;
        int bb = row / 2624, rr = row - bb * 2624;
        int py, px;
        if (rr < 672)       { py = rr / 168;               px = rr % 168; }
        else if (rr < 1344) { int r2 = rr - 672; py = 164 + r2 / 168; px = r2 % 168; }
        else                { int rm = rr - 1344; py = 4 + rm / 8; int q = rm & 7;
                              px = (q < 4) ? q : 160 + q; }
        bf16x8 v;
#pragma unroll
        for (int j = 0; j < 8; ++j) v[j] = (__bf16)kv_b[seg * 8 + j];
        *(bf16x8*)(KVb + ((long)((bb * CPH + py) * CPH + px)) * 384 + seg * 8) = v;
    }
}

// ---------------------------------------------------------------------------
// Fused QGKV GEMM: M=51200 image rows, N=768 (Q|G|KV), K=192.
// BM=BN=BK=64, reg-staged XOR-swizzled LDS, double-buffered.
// Epilogue via LDS transpose -> coalesced bf16x8 stores (buffer uniform in bn).
// ---------------------------------------------------------------------------
__global__ __launch_bounds__(256)
void gemm_f_k(const float* __restrict__ x, const __bf16* __restrict__ Wt,
              const float* __restrict__ b768,
              __bf16* __restrict__ Qb, __bf16* __restrict__ Gb,
              __bf16* __restrict__ KVb)
{
    __shared__ __bf16 As[2][4096];
    __shared__ __bf16 Bs[2][4096];

    const int bid = blockIdx.x;                 // 9600 = 8 * 1200
    const int v = (bid & 7) * 1200 + (bid >> 3);
    const int bm = v / 12, bn = v - bm * 12;

    const int t = threadIdx.x, lane = t & 63, wv = t >> 6;
    const int l15 = lane & 15, l4 = lane >> 4;
    const int row = t >> 2, gp = t & 3;
    const int swz = row & 7;
    const int d0 = row * 64 + ((2 * gp) ^ swz) * 8;
    const int d1 = row * 64 + ((2 * gp + 1) ^ swz) * 8;

    const float*  asrc = x  + (long)(bm * 64 + row) * 192 + gp * 16;
    const __bf16* bsrc = Wt + (long)(bn * 64 + row) * 192 + gp * 16;

    float4 fa0, fa1, fa2, fa3;
    bf16x8 wb0, wb1;
    auto ld = [&](int kt) {
        const float* a = asrc + kt * 64;
        fa0 = ((const float4*)a)[0]; fa1 = ((const float4*)a)[1];
        fa2 = ((const float4*)a)[2]; fa3 = ((const float4*)a)[3];
        wb0 = *(const bf16x8*)(bsrc + kt * 64);
        wb1 = *(const bf16x8*)(bsrc + kt * 64 + 8);
    };
    auto st = [&](int buf) {
        bf16x8 g0, g1;
        g0[0] = (__bf16)fa0.x; g0[1] = (__bf16)fa0.y; g0[2] = (__bf16)fa0.z; g0[3] = (__bf16)fa0.w;
        g0[4] = (__bf16)fa1.x; g0[5] = (__bf16)fa1.y; g0[6] = (__bf16)fa1.z; g0[7] = (__bf16)fa1.w;
        g1[0] = (__bf16)fa2.x; g1[1] = (__bf16)fa2.y; g1[2] = (__bf16)fa2.z; g1[3] = (__bf16)fa2.w;
        g1[4] = (__bf16)fa3.x; g1[5] = (__bf16)fa3.y; g1[6] = (__bf16)fa3.z; g1[7] = (__bf16)fa3.w;
        *(bf16x8*)&As[buf][d0] = g0;
        *(bf16x8*)&As[buf][d1] = g1;
        *(bf16x8*)&Bs[buf][d0] = wb0;
        *(bf16x8*)&Bs[buf][d1] = wb1;
    };

    const int qm = (wv >> 1) * 32, qn = (wv & 1) * 32;
    f32x4 acc[2][2];
#pragma unroll
    for (int i = 0; i < 2; ++i)
#pragma unroll
        for (int j = 0; j < 2; ++j) acc[i][j] = f32x4{0.f, 0.f, 0.f, 0.f};

    ld(0);
    for (int kt = 0; kt < 3; ++kt) {
        const int buf = kt & 1;
        st(buf);
        if (kt < 2) ld(kt + 1);
        __syncthreads();
#pragma unroll
        for (int s = 0; s < 2; ++s) {
            bf16x8 af[2], bfr[2];
#pragma unroll
            for (int mi = 0; mi < 2; ++mi)
                af[mi] = *(const bf16x8*)&As[buf][(qm + mi * 16 + l15) * 64 +
                                                 (((s * 4 + l4) ^ (l15 & 7)) * 8)];
#pragma unroll
            for (int ni = 0; ni < 2; ++ni)
                bfr[ni] = *(const bf16x8*)&Bs[buf][(qn + ni * 16 + l15) * 64 +
                                                   (((s * 4 + l4) ^ (l15 & 7)) * 8)];
#pragma unroll
            for (int mi = 0; mi < 2; ++mi)
#pragma unroll
                for (int ni = 0; ni < 2; ++ni)
                    acc[mi][ni] = MFMA16(af[mi], bfr[ni], acc[mi][ni]);
        }
        __syncthreads();
    }

    // ---- epilogue via LDS transpose (reuse As; [64][80] bf16, conflict-free) ----
    __bf16* epi = &As[0][0];
    float bv0 = b768[bn * 64 + qn + l15];
    float bv1 = b768[bn * 64 + qn + 16 + l15];
#pragma unroll
    for (int mi = 0; mi < 2; ++mi)
#pragma unroll
        for (int ni = 0; ni < 2; ++ni)
#pragma unroll
            for (int r = 0; r < 4; ++r) {
                int rowl = qm + mi * 16 + l4 * 4 + r;
                int coll = qn + ni * 16 + l15;
                epi[rowl * 80 + coll] =
                    (__bf16)(acc[mi][ni][r] + (ni ? bv1 : bv0));
            }
    __syncthreads();
#pragma unroll
    for (int k = 0; k < 2; ++k) {
        int rid = t * 2 + k;
        int rowl = rid >> 3, seg = rid & 7;
        bf16x8 vv = *(const bf16x8*)&epi[rowl * 80 + seg * 8];
        int rowg = bm * 64 + rowl;
        int bb = rowg / 25600, rr = rowg - bb * 25600;
        int y = rr / 160, xx = rr - y * 160;
        int cg = bn * 64 + seg * 8;
        if (bn < 6) {
            int win = bb * 100 + (y >> 4) * 10 + (xx >> 4);
            long widx = ((long)win * 256 + (y & 15) * 16 + (xx & 15)) * 192;
            if (bn < 3) *(bf16x8*)(Qb + widx + cg) = vv;
            else        *(bf16x8*)(Gb + widx + cg - 192) = vv;
        } else {
            long kidx = ((long)((bb * CPH + y + 4) * CPH + (xx + 4))) * 384;
            *(bf16x8*)(KVb + kidx + cg - 384) = vv;
        }
    }
}

// ---------------------------------------------------------------------------
// Projection GEMM: M=51200 window rows (Yb), N=192, K=192; out f32 image.
// ---------------------------------------------------------------------------
__global__ __launch_bounds__(256)
void gemm_p_k(const __bf16* __restrict__ Yb, const __bf16* __restrict__ Wp,
              const float* __restrict__ pb, float* __restrict__ of)
{
    __shared__ __bf16 As[2][4096];
    __shared__ __bf16 Bs[2][4096];

    const int bid = blockIdx.x;                 // 2400 = 8 * 300
    const int v = (bid & 7) * 300 + (bid >> 3);
    const int bm = v / 3, bn = v - bm * 3;

    const int t = threadIdx.x, lane = t & 63, wv = t >> 6;
    const int l15 = lane & 15, l4 = lane >> 4;
    const int row = t >> 2, gp = t & 3;
    const int swz = row & 7;
    const int d0 = row * 64 + ((2 * gp) ^ swz) * 8;
    const int d1 = row * 64 + ((2 * gp + 1) ^ swz) * 8;

    const __bf16* asrc = Yb + (long)(bm * 64 + row) * 192 + gp * 16;
    const __bf16* bsrc = Wp + (long)(bn * 64 + row) * 192 + gp * 16;

    bf16x8 a0, a1, wb0, wb1;
    auto ld = [&](int kt) {
        a0  = *(const bf16x8*)(asrc + kt * 64);
        a1  = *(const bf16x8*)(asrc + kt * 64 + 8);
        wb0 = *(const bf16x8*)(bsrc + kt * 64);
        wb1 = *(const bf16x8*)(bsrc + kt * 64 + 8);
    };
    auto st = [&](int buf) {
        *(bf16x8*)&As[buf][d0] = a0;
        *(bf16x8*)&As[buf][d1] = a1;
        *(bf16x8*)&Bs[buf][d0] = wb0;
        *(bf16x8*)&Bs[buf][d1] = wb1;
    };

    const int qm = (wv >> 1) * 32, qn = (wv & 1) * 32;
    f32x4 acc[2][2];
#pragma unroll
    for (int i = 0; i < 2; ++i)
#pragma unroll
        for (int j = 0; j < 2; ++j) acc[i][j] = f32x4{0.f, 0.f, 0.f, 0.f};

    ld(0);
    for (int kt = 0; kt < 3; ++kt) {
        const int buf = kt & 1;
        st(buf);
        if (kt < 2) ld(kt + 1);
        __syncthreads();
#pragma unroll
        for (int s = 0; s < 2; ++s) {
            bf16x8 af[2], bfr[2];
#pragma unroll
            for (int mi = 0; mi < 2; ++mi)
                af[mi] = *(const bf16x8*)&As[buf][(qm + mi * 16 + l15) * 64 +
                                                 (((s * 4 + l4) ^ (l15 & 7)) * 8)];
#pragma unroll
            for (int ni = 0; ni < 2; ++ni)
                bfr[ni] = *(const bf16x8*)&Bs[buf][(qn + ni * 16 + l15) * 64 +
                                                   (((s * 4 + l4) ^ (l15 & 7)) * 8)];
#pragma unroll
            for (int mi = 0; mi < 2; ++mi)
#pragma unroll
                for (int ni = 0; ni < 2; ++ni)
                    acc[mi][ni] = MFMA16(af[mi], bfr[ni], acc[mi][ni]);
        }
        __syncthreads();
    }

#pragma unroll
    for (int mi = 0; mi < 2; ++mi) {
#pragma unroll
        for (int r = 0; r < 4; ++r) {
            int rowg = bm * 64 + qm + mi * 16 + l4 * 4 + r;   // window row
            int win = rowg >> 8, q = rowg & 255;
            int bb = win / 100, wr = win % 100;
            int y = (wr / 10) * 16 + (q >> 4), xx = (wr % 10) * 16 + (q & 15);
            long oidx = ((long)((bb * CH + y) * CW + xx)) * 192;
#pragma unroll
            for (int ni = 0; ni < 2; ++ni) {
                int cg = bn * 64 + qn + ni * 16 + l15;
                of[oidx + cg] = acc[mi][ni][r] + pb[cg];
            }
        }
    }
}

// ---------------------------------------------------------------------------
// Attention (R7 structure, f32 bias): 512-thread blocks (8 waves x 32 q-rows),
// whole-window K + V^T staged to LDS ONCE, zero-barrier 18-tile main loop,
// K-frag + f32 bias prefetched one tile ahead.
// ---------------------------------------------------------------------------
__global__ __launch_bounds__(512, 4)
void attn9_k(const __bf16* __restrict__ Q, const __bf16* __restrict__ KV,
             const __bf16* __restrict__ G, const float* __restrict__ BTf,
             const u32* __restrict__ MT, __bf16* __restrict__ Y)
{
    __shared__ __bf16 Ks[576][36];   // 41,472 B
    __shared__ __bf16 Vt[32][580];   // 37,120 B

    const int bid = blockIdx.x;      // 1200 = 8 * 150
    const int xs = bid & 7, ii = bid >> 3;
    const int win = xs * 25 + ii / 6;
    const int head = ii % 6;

    const int bb = win / 100, wr = win % 100, wy = wr / 10, wx = wr % 10;
    const int cy = (wy == 0) ? 0 : ((wy == 9) ? 2 : 1);
    const int cx = (wx == 0) ? 0 : ((wx == 9) ? 2 : 1);
    const int cls = cy * 3 + cx;
    const int t = threadIdx.x, lane = t & 63, wv = t >> 6;
    const int l31 = lane & 31, hi = lane >> 5;

    // ---- stage whole-window K and V^T (one time) ----
    {
        const int pos0 = t >> 3, seg = t & 7;
        int oy = pos0 / 24, ox = pos0 - oy * 24;
        const long rowbase = ((long)((bb * CPH + wy * 16) * CPH + wx * 16)) * 384
                             + head * CD;
        int pos = pos0;
#pragma unroll
        for (int r = 0; r < 9; ++r) {
            const __bf16* p = KV + rowbase + (long)(oy * CPH + ox) * 384;
            if (seg < 4) {
                bf16x8 k8 = *(const bf16x8*)(p + seg * 8);
                *(bf16x8*)&Ks[pos][seg * 8] = k8;
            } else {
                bf16x8 v8 = *(const bf16x8*)(p + 192 + (seg - 4) * 8);
#pragma unroll
                for (int j = 0; j < 8; ++j) Vt[(seg - 4) * 8 + j][pos] = v8[j];
            }
            pos += 64;
            oy += 2; ox += 16;
            if (ox >= 24) { ox -= 24; oy += 1; }
        }
    }

    // Q fragments (this wave's 32 q-rows)
    bf16x8 qf0, qf1;
    {
        const __bf16* qb = Q + ((long)win * CNQ + wv * 32 + l31) * CC + head * CD;
        qf0 = *(const bf16x8*)(qb + hi * 8);
        qf1 = *(const bf16x8*)(qb + 16 + hi * 8);
    }
    const float* btb = BTf + (long)((head * 8 + wv) * 18) * 1024 + (long)lane * 16;
    f32x16 bA = *(const f32x16*)btb;

    __syncthreads();   // the ONLY barrier

    f32x16 o = {};
    float srun = 0.f;

    const char* kbase = (const char*)&Ks[0][0] + l31 * 72 + hi * 16;
    const char* vbase = (const char*)&Vt[0][0] + l31 * 1160 + hi * 8;

    bf16x8 kc0 = *(const bf16x8*)(kbase);
    bf16x8 kc1 = *(const bf16x8*)(kbase + 32);

    for (int tt = 0; tt < 18; ++tt) {
        // prefetch next tile's K frags (LDS) + f32 bias (L2) one tile ahead
        bf16x8 kn0, kn1;
        f32x16 bB;
        if (tt < 17) {
            const char* kn = kbase + (tt + 1) * 2304;
            kn0 = *(const bf16x8*)(kn);
            kn1 = *(const bf16x8*)(kn + 32);
            bB  = *(const f32x16*)(btb + (long)(tt + 1) * 1024);
        }

        // V fragments for this tile (conflict-free b64 reads)
        const char* vp = vbase + tt * 64;
        bf16x4 v0 = *(const bf16x4*)(vp);
        bf16x4 v1 = *(const bf16x4*)(vp + 16);
        bf16x4 v2 = *(const bf16x4*)(vp + 32);
        bf16x4 v3 = *(const bf16x4*)(vp + 48);
        bf16x8 vf0, vf1;
#pragma unroll
        for (int j = 0; j < 4; ++j) {
            vf0[j] = v0[j]; vf0[4 + j] = v1[j];
            vf1[j] = v2[j]; vf1[4 + j] = v3[j];
        }

        // scores = bias + K^T Q   (bias is the MFMA C-input, no cvt needed)
        f32x16 stv = bA;
        __builtin_amdgcn_s_setprio(1);
        stv = MFMA32(kc0, qf0, stv);
        stv = MFMA32(kc1, qf1, stv);
        __builtin_amdgcn_s_setprio(0);

        const bool needm = (cx != 1) || (cy == 0 && tt < 3) || (cy == 2 && tt >= 15);
        u32 m = 0xFFFFFFFFu;
        if (needm) m = MT[(cls * 18 + tt) * 64 + lane];

        float p[16];
#pragma unroll
        for (int r = 0; r < 16; ++r) p[r] = exp2f(stv[r]);
        if (needm) {
#pragma unroll
            for (int r = 0; r < 16; ++r)
                p[r] = (m & (1u << r)) ? p[r] : 0.0f;
        }
        float s = 0.f;
#pragma unroll
        for (int r = 0; r < 16; ++r) s += p[r];
        srun += s;

        bf16x8 pa0, pa1;
#pragma unroll
        for (int j = 0; j < 8; ++j) {
            pa0[j] = (__bf16)p[j];
            pa1[j] = (__bf16)p[8 + j];
        }

        __builtin_amdgcn_s_setprio(1);
        o = MFMA32(vf0, pa0, o);
        o = MFMA32(vf1, pa1, o);
        __builtin_amdgcn_s_setprio(0);

        kc0 = kn0; kc1 = kn1; bA = bB;
    }

    // ---- epilogue: cross-half sum, normalize, gate, store ----
    srun += __shfl_xor(srun, 32);
    float rs = 1.0f / srun;
    long base = ((long)win * CNQ + wv * 32 + l31) * CC + head * CD;
    const __bf16* gp2 = G + base;
    __bf16* yp = Y + base;
#pragma unroll
    for (int g = 0; g < 4; ++g) {
        bf16x4 gv = *(const bf16x4*)(gp2 + g * 8 + 4 * hi);
        bf16x4 ov;
#pragma unroll
        for (int j = 0; j < 4; ++j)
            ov[j] = (__bf16)(o[g * 4 + j] * rs * (float)gv[j]);
        *(bf16x4*)(yp + g * 8 + 4 * hi) = ov;
    }
}

// ---------------------------------------------------------------------------
extern "C" void kernel_launch(void* const* d_in, const int* in_sizes, int n_in,
                              void* d_out, int out_size, void* d_ws, size_t ws_size,
                              hipStream_t stream)
{
    (void)in_sizes; (void)n_in; (void)out_size; (void)ws_size;
    const float* x    = (const float*)d_in[0];
    const int*   rpi  = (const int*)  d_in[1];
    // d_in[2] = attn_mask (recomputed analytically)
    const float* q_w  = (const float*)d_in[3];
    const float* q_b  = (const float*)d_in[4];
    const float* kv_w = (const float*)d_in[5];
    const float* kv_b = (const float*)d_in[6];
    const float* btab = (const float*)d_in[7];
    const float* g_w  = (const float*)d_in[8];
    const float* g_b  = (const float*)d_in[9];
    const float* p_w  = (const float*)d_in[10];
    const float* p_b  = (const float*)d_in[11];
    float* out = (float*)d_out;

    char* ws = (char*)d_ws;
    __bf16* Qb  = (__bf16*)(ws);                  // 19,660,800
    __bf16* KVb = (__bf16*)(ws + 19660800);       // 43,352,064
    __bf16* Gb  = (__bf16*)(ws + 63012864);       // 19,660,800
    __bf16* Yb  = (__bf16*)(ws + 82673664);       // 19,660,800
    float*  BTf = (float*) (ws + 102334464);      // 3,538,944
    u32*    MT  = (u32*)   (ws + 105873408);      // 41,472
    __bf16* Wt  = (__bf16*)(ws + 105914880);      // 294,912
    __bf16* Wp  = (__bf16*)(ws + 106209792);      // 73,728
    float*  b768= (float*) (ws + 106283520);      // 3,072
    float*  pb  = (float*) (ws + 106286592);      // 768

    prep_k<<<1965, 256, 0, stream>>>(rpi, btab, q_w, g_w, kv_w, p_w,
                                     q_b, g_b, kv_b, p_b,
                                     BTf, MT, Wt, Wp, b768, pb, KVb);
    gemm_f_k<<<9600, 256, 0, stream>>>(x, Wt, b768, Qb, Gb, KVb);
    attn9_k<<<1200, 512, 0, stream>>>(Qb, KVb, Gb, BTf, MT, Yb);
    gemm_p_k<<<2400, 256, 0, stream>>>(Yb, Wp, pb, out);
}